// Round 1
// 2699.126 us; speedup vs baseline: 1.0571x; 1.0571x over previous
//
#include <hip/hip_runtime.h>
#include <hip/hip_bf16.h>
#include <math.h>

// ---- problem constants (BERT-base, B=8, S=512) ----
#define S_LEN   512
#define HID     768
#define NLAYER  12
#define NHEAD   12
#define FFN_DIM 3072
#define HDIM    64
#define NTOK    4096   // B*S
#define QKVN    2304   // 3*HID

typedef __bf16 bf16x8 __attribute__((ext_vector_type(8)));
typedef __bf16 bf16x4 __attribute__((ext_vector_type(4)));
typedef float  f32x4  __attribute__((ext_vector_type(4)));

typedef __attribute__((address_space(1))) const unsigned int gas_u32;
typedef __attribute__((address_space(3))) unsigned int las_u32;

#define MFMA16(a, b, c) __builtin_amdgcn_mfma_f32_16x16x32_bf16((a), (b), (c), 0, 0, 0)

// ---------------------------------------------------------------------------
// fast exact-erf GELU: A&S 7.1.26, max abs err 1.5e-7 (invisible in bf16).
// Uniform control flow: 1 rcp + 1 exp + ~8 fma, no divergent tails.
// ---------------------------------------------------------------------------
__device__ __forceinline__ float fast_gelu(float v) {
  float ax = fabsf(v) * 0.70710678118654752f;
  float t  = __builtin_amdgcn_rcpf(fmaf(0.3275911f, ax, 1.0f));
  float p  = fmaf(fmaf(fmaf(fmaf(1.061405429f, t, -1.453152027f), t,
                            1.421413741f), t, -0.284496736f), t, 0.254829592f);
  float e  = __expf(-ax * ax);
  float er = 1.0f - p * t * e;
  er = copysignf(er, v);
  return 0.5f * v * (1.0f + er);
}

// ---------------------------------------------------------------------------
// block-wide reduction of (sum, sumsq) over 256 threads (4 waves of 64)
// ---------------------------------------------------------------------------
__device__ __forceinline__ void block_reduce_2(float& sum, float& sq) {
  __shared__ float sd[8];
  int lane = threadIdx.x & 63;
  int wid  = threadIdx.x >> 6;
  #pragma unroll
  for (int off = 32; off > 0; off >>= 1) {
    sum += __shfl_down(sum, off, 64);
    sq  += __shfl_down(sq,  off, 64);
  }
  if (lane == 0) { sd[wid] = sum; sd[4 + wid] = sq; }
  __syncthreads();
  sum = sd[0] + sd[1] + sd[2] + sd[3];
  sq  = sd[4] + sd[5] + sd[6] + sd[7];
}

// ---------------------------------------------------------------------------
// mask bias: -10000 where input_id == 0 (padding), else 0
// ---------------------------------------------------------------------------
__global__ __launch_bounds__(256) void mask_kernel(const int* __restrict__ ids,
                                                   float* __restrict__ mb) {
  int i = blockIdx.x * 256 + threadIdx.x;
  if (i < NTOK) mb[i] = (ids[i] == 0) ? -10000.0f : 0.0f;
}

// ---------------------------------------------------------------------------
// pack q/k/v biases for ALL layers into [L][2304] once
// ---------------------------------------------------------------------------
__global__ __launch_bounds__(256) void pack_qkvb_kernel(
    const float* __restrict__ bq, const float* __restrict__ bk,
    const float* __restrict__ bv, float* __restrict__ out) {
  int i = blockIdx.x * 256 + threadIdx.x;
  if (i >= NLAYER * QKVN) return;
  int l = i / QKVN, c = i % QKVN;
  float v = (c < HID) ? bq[l * HID + c]
          : (c < 2 * HID) ? bk[l * HID + c - HID]
                          : bv[l * HID + c - 2 * HID];
  out[i] = v;
}

// ---------------------------------------------------------------------------
// embeddings + layernorm -> fp32 h and bf16 h
// ---------------------------------------------------------------------------
__global__ __launch_bounds__(256) void embed_ln_kernel(
    const int* __restrict__ ids, const int* __restrict__ tids,
    const float* __restrict__ we, const float* __restrict__ pe,
    const float* __restrict__ te, const float* __restrict__ gamma,
    const float* __restrict__ beta, float* __restrict__ out32,
    __bf16* __restrict__ out16) {
  int t = blockIdx.x;
  int s = t & (S_LEN - 1);
  int id = ids[t];
  int tp = tids[t];
  float x[3];
  #pragma unroll
  for (int i = 0; i < 3; ++i) {
    int c = threadIdx.x + i * 256;
    x[i] = we[(size_t)id * HID + c] + pe[(size_t)s * HID + c] +
           te[(size_t)tp * HID + c];
  }
  float sum = x[0] + x[1] + x[2];
  float sq  = x[0]*x[0] + x[1]*x[1] + x[2]*x[2];
  block_reduce_2(sum, sq);
  float mu   = sum * (1.0f / HID);
  float var  = sq * (1.0f / HID) - mu * mu;
  float rstd = rsqrtf(var + 1e-12f);
  #pragma unroll
  for (int i = 0; i < 3; ++i) {
    int c = threadIdx.x + i * 256;
    float v = (x[i] - mu) * rstd * gamma[c] + beta[c];
    out32[(size_t)t * HID + c] = v;
    out16[(size_t)t * HID + c] = (__bf16)v;
  }
}

// ---------------------------------------------------------------------------
// residual add (+ optional third partial) + layernorm -> fp32 and bf16
// ---------------------------------------------------------------------------
__global__ __launch_bounds__(256) void add_ln_kernel(
    const float* __restrict__ a, const float* __restrict__ b,
    const float* __restrict__ c,
    const float* __restrict__ gamma, const float* __restrict__ beta,
    float* __restrict__ out32, __bf16* __restrict__ out16) {
  int t = blockIdx.x;
  float x[3];
  #pragma unroll
  for (int i = 0; i < 3; ++i) {
    int ci = threadIdx.x + i * 256;
    size_t idx = (size_t)t * HID + ci;
    x[i] = a[idx] + b[idx];
    if (c) x[i] += c[idx];
  }
  float sum = x[0] + x[1] + x[2];
  float sq  = x[0]*x[0] + x[1]*x[1] + x[2]*x[2];
  block_reduce_2(sum, sq);
  float mu   = sum * (1.0f / HID);
  float var  = sq * (1.0f / HID) - mu * mu;
  float rstd = rsqrtf(var + 1e-12f);
  #pragma unroll
  for (int i = 0; i < 3; ++i) {
    int ci = threadIdx.x + i * 256;
    float v = (x[i] - mu) * rstd * gamma[ci] + beta[ci];
    out32[(size_t)t * HID + ci] = v;
    out16[(size_t)t * HID + ci] = (__bf16)v;
  }
}

// ---------------------------------------------------------------------------
// transpose + fp32->bf16: src [R][C] f32 -> dst [C][R] bf16. blockIdx.z=layer.
// ---------------------------------------------------------------------------
__global__ __launch_bounds__(256) void tcvt_kernel(
    const float* __restrict__ src, __bf16* __restrict__ dst, int R, int C) {
  __shared__ float tile[32][33];
  int l = blockIdx.z;
  src += (size_t)l * R * C;
  dst += (size_t)l * R * C;
  int c0 = blockIdx.x * 32, r0 = blockIdx.y * 32;
  int tx = threadIdx.x & 31, ty = threadIdx.x >> 5;  // ty 0..7
  #pragma unroll
  for (int i = 0; i < 4; ++i) {
    int r = ty + i * 8;
    tile[r][tx] = src[(size_t)(r0 + r) * C + c0 + tx];
  }
  __syncthreads();
  #pragma unroll
  for (int i = 0; i < 4; ++i) {
    int r = ty + i * 8;
    dst[(size_t)(c0 + r) * R + r0 + tx] = (__bf16)tile[tx][r];
  }
}

// 4 HxH transposes (wq,wk,wv,wo), blockIdx.z = layer*4 + sel.
// dqkv layout: [layer][3*HID][HID] (q,k,v stacked); dwo: [layer][HID][HID].
__global__ __launch_bounds__(256) void tcvt4_kernel(
    const float* __restrict__ sq, const float* __restrict__ sk,
    const float* __restrict__ sv, const float* __restrict__ so,
    __bf16* __restrict__ dqkv, __bf16* __restrict__ dwo) {
  __shared__ float tile[32][33];
  const size_t WHH = (size_t)HID * HID;
  int z = blockIdx.z;
  int l = z >> 2, sel = z & 3;
  const float* src = ((sel == 0) ? sq : (sel == 1) ? sk : (sel == 2) ? sv : so)
                     + (size_t)l * WHH;
  __bf16* dst = (sel < 3) ? dqkv + (size_t)l * 3 * WHH + (size_t)sel * WHH
                          : dwo + (size_t)l * WHH;
  int c0 = blockIdx.x * 32, r0 = blockIdx.y * 32;
  int tx = threadIdx.x & 31, ty = threadIdx.x >> 5;
  #pragma unroll
  for (int i = 0; i < 4; ++i) {
    int r = ty + i * 8;
    tile[r][tx] = src[(size_t)(r0 + r) * HID + c0 + tx];
  }
  __syncthreads();
  #pragma unroll
  for (int i = 0; i < 4; ++i) {
    int r = ty + i * 8;
    dst[(size_t)(c0 + r) * HID + r0 + tx] = (__bf16)tile[tx][r];
  }
}

// ---------------------------------------------------------------------------
// m97-style bf16 MFMA GEMM: C[M,N] = A[M,K] @ Bt[N,K]^T + bias.
// 128xTN tile (TN=128 or 64), BK=64, 256 threads.
//   TN=128: waves 2x2, each 64x64 (4x4 frags).  TN=64: waves 4x1, each 32x64.
// Staging: global_load_lds 16B, XOR swizzle on the GLOBAL source address
// (LDS dest is wave-uniform + lane*16), so frag ds_read_b128 is 2-way (free).
// MODE 0: f32 out (split-K via blockIdx.z: chunk kz covers K rows
//         [kz*kchunk, (kz+1)*kchunk), partial kz written to Cout + kz*M*N,
//         bias only on kz==0);
// MODE 1: bf16 out; MODE 2: bf16 out + fast exact GELU;
// MODE 3: bf16 out, but cols >= 2*HID (the V block of QKV) go directly to
//         vtout[b][h][d][s] (fused V-transpose, packed 4 x bf16 over s).
// ---------------------------------------------------------------------------
template <int MODE, int TN>
__global__ __launch_bounds__(256) void mfma_gemm(
    const __bf16* __restrict__ A, const __bf16* __restrict__ Bt,
    const float* __restrict__ bias, void* __restrict__ Cout,
    __bf16* __restrict__ vtout, int M, int N, int K, int kchunk) {
  constexpr int AI = 4;        // global_load_lds insts/wave for A (128 rows)
  constexpr int BI = TN / 32;  // and for B (TN rows)
  constexpr int RT = (TN == 128) ? 4 : 2;
  constexpr int CT = 4;
  __shared__ __align__(16) __bf16 As[128 * 64];
  __shared__ __align__(16) __bf16 Bs[TN * 64];
  const int tid = threadIdx.x;
  const int w = tid >> 6, lane = tid & 63;
  const int l15 = lane & 15, quad = lane >> 4;
  const int m0 = blockIdx.y * 128, n0 = blockIdx.x * TN;
  const int kz = blockIdx.z;
  const int lr = lane >> 3;               // row-within-8 for staging
  const int colg = (lane & 7) ^ lr;       // swizzled global chunk column

  const int wr = (TN == 128) ? (w >> 1) * 64 : w * 32;  // wave row offset
  const int wc = (TN == 128) ? (w & 1) * 64 : 0;        // wave col offset

  A  += (size_t)kz * kchunk;   // shift within row (row stride stays K)
  Bt += (size_t)kz * kchunk;

  f32x4 acc[RT][CT];
  const f32x4 z4 = {0.f, 0.f, 0.f, 0.f};
  #pragma unroll
  for (int i = 0; i < RT; ++i)
    #pragma unroll
    for (int j = 0; j < CT; ++j) acc[i][j] = z4;

  const __bf16* Ag = A  + (size_t)(m0 + 8 * AI * w + lr) * K + colg * 8;
  const __bf16* Bg = Bt + (size_t)(n0 + 8 * BI * w + lr) * K + colg * 8;
  __bf16* Al = As + 512 * AI * w;
  __bf16* Bl = Bs + 512 * BI * w;

  for (int kt = 0; kt < kchunk; kt += 64) {
    #pragma unroll
    for (int i = 0; i < AI; ++i)
      __builtin_amdgcn_global_load_lds(
          (gas_u32*)(Ag + (size_t)(8 * i) * K + kt),
          (las_u32*)(Al + 512 * i), 16, 0, 0);
    #pragma unroll
    for (int i = 0; i < BI; ++i)
      __builtin_amdgcn_global_load_lds(
          (gas_u32*)(Bg + (size_t)(8 * i) * K + kt),
          (las_u32*)(Bl + 512 * i), 16, 0, 0);
    __syncthreads();
    #pragma unroll
    for (int kc = 0; kc < 2; ++kc) {
      bf16x8 af[RT], bfr[CT];
      #pragma unroll
      for (int rt = 0; rt < RT; ++rt) {
        int row = wr + rt * 16 + l15;
        af[rt] = *(const bf16x8*)&As[(row * 8 + ((kc * 4 + quad) ^ (row & 7))) * 8];
      }
      #pragma unroll
      for (int ct = 0; ct < CT; ++ct) {
        int col = wc + ct * 16 + l15;
        bfr[ct] = *(const bf16x8*)&Bs[(col * 8 + ((kc * 4 + quad) ^ (col & 7))) * 8];
      }
      #pragma unroll
      for (int rt = 0; rt < RT; ++rt)
        #pragma unroll
        for (int ct = 0; ct < CT; ++ct)
          acc[rt][ct] = MFMA16(af[rt], bfr[ct], acc[rt][ct]);
    }
    __syncthreads();
  }

  float* outf = (float*)Cout + (size_t)kz * M * N;  // split-K partial (MODE 0)
  #pragma unroll
  for (int rt = 0; rt < RT; ++rt) {
    int rbase = m0 + wr + rt * 16 + quad * 4;
    #pragma unroll
    for (int ct = 0; ct < CT; ++ct) {
      int col = n0 + wc + ct * 16 + l15;
      float bv = (kz == 0) ? bias[col] : 0.0f;
      float vv[4];
      #pragma unroll
      for (int r = 0; r < 4; ++r) {
        float v = acc[rt][ct][r] + bv;
        if (MODE == 2) v = fast_gelu(v);
        vv[r] = v;
      }
      if (MODE == 3 && col >= 2 * HID) {
        // fused V-transpose: vt[(b*NHEAD+h)*HDIM + d][s], rbase%4==0 so the
        // 4 consecutive s fit one aligned 8B packed store.
        int cc = col - 2 * HID;
        int hh = cc >> 6, d = cc & 63;
        int bb = rbase >> 9, s0 = rbase & (S_LEN - 1);
        bf16x4 pk = {(__bf16)vv[0], (__bf16)vv[1], (__bf16)vv[2], (__bf16)vv[3]};
        *(bf16x4*)(vtout +
                   (((size_t)(bb * NHEAD + hh) * HDIM + d) * S_LEN + s0)) = pk;
      } else {
        #pragma unroll
        for (int r = 0; r < 4; ++r) {
          if (MODE == 0)
            outf[(size_t)(rbase + r) * N + col] = vv[r];
          else
            ((__bf16*)Cout)[(size_t)(rbase + r) * N + col] = (__bf16)vv[r];
        }
      }
    }
  }
}

// ---------------------------------------------------------------------------
// MFMA attention: block = (64 q-rows, head, batch); wave w owns 16 q-rows.
// ---------------------------------------------------------------------------
__global__ __launch_bounds__(256) void attn_mfma(
    const __bf16* __restrict__ qkv,  // [tok][2304], q at +0, k at +768
    const __bf16* __restrict__ vt,   // [b][h][64][512]
    const float* __restrict__ mb,    // [B*S]
    __bf16* __restrict__ ctx) {      // [tok][768]
  constexpr int PLD = 264;
  __shared__ __align__(16) __bf16 Plds[4][16 * PLD];
  const int tid = threadIdx.x;
  const int wv = tid >> 6, lane = tid & 63;
  const int l15 = lane & 15, quad = lane >> 4;
  const int b = blockIdx.z, hh = blockIdx.y, q0 = blockIdx.x * 64;
  const f32x4 z4 = {0.f, 0.f, 0.f, 0.f};

  size_t qoff = ((size_t)(b * S_LEN) + q0 + wv * 16 + l15) * QKVN + hh * HDIM;
  bf16x8 qa0 = *(const bf16x8*)(qkv + qoff + quad * 8);
  bf16x8 qa1 = *(const bf16x8*)(qkv + qoff + 32 + quad * 8);

  f32x4 sc[32];
  #pragma unroll
  for (int kt = 0; kt < 32; ++kt) {
    size_t koff = ((size_t)(b * S_LEN) + kt * 16 + l15) * QKVN + HID + hh * HDIM;
    bf16x8 kb0 = *(const bf16x8*)(qkv + koff + quad * 8);
    bf16x8 kb1 = *(const bf16x8*)(qkv + koff + 32 + quad * 8);
    f32x4 t = MFMA16(qa0, kb0, z4);
    sc[kt] = MFMA16(qa1, kb1, t);
  }

  float mx[4] = {-1e30f, -1e30f, -1e30f, -1e30f};
  #pragma unroll
  for (int kt = 0; kt < 32; ++kt) {
    float mval = mb[b * S_LEN + kt * 16 + l15];
    #pragma unroll
    for (int r = 0; r < 4; ++r) {
      float x = sc[kt][r] * 0.125f + mval;
      sc[kt][r] = x;
      mx[r] = fmaxf(mx[r], x);
    }
  }
  #pragma unroll
  for (int m = 1; m < 16; m <<= 1)
    #pragma unroll
    for (int r = 0; r < 4; ++r) mx[r] = fmaxf(mx[r], __shfl_xor(mx[r], m, 64));

  float sm[4] = {0.f, 0.f, 0.f, 0.f};
  #pragma unroll
  for (int kt = 0; kt < 32; ++kt)
    #pragma unroll
    for (int r = 0; r < 4; ++r) {
      float e = __expf(sc[kt][r] - mx[r]);
      sc[kt][r] = e;
      sm[r] += e;
    }
  #pragma unroll
  for (int m = 1; m < 16; m <<= 1)
    #pragma unroll
    for (int r = 0; r < 4; ++r) sm[r] += __shfl_xor(sm[r], m, 64);
  float inv[4];
  #pragma unroll
  for (int r = 0; r < 4; ++r) inv[r] = 1.0f / sm[r];

  __bf16* pbuf = &Plds[wv][0];
  const __bf16* vbase = vt + (size_t)(b * NHEAD + hh) * HDIM * S_LEN;
  f32x4 oc[4] = {z4, z4, z4, z4};
  #pragma unroll
  for (int half = 0; half < 2; ++half) {
    #pragma unroll
    for (int kt2 = 0; kt2 < 16; ++kt2) {
      int kt = half * 16 + kt2;
      #pragma unroll
      for (int r = 0; r < 4; ++r)
        pbuf[(quad * 4 + r) * PLD + kt2 * 16 + l15] = (__bf16)(sc[kt][r] * inv[r]);
    }
    #pragma unroll
    for (int kc = 0; kc < 8; ++kc) {
      bf16x8 pa = *(const bf16x8*)&pbuf[l15 * PLD + kc * 32 + quad * 8];
      int kbase = half * 256 + kc * 32;
      #pragma unroll
      for (int ct = 0; ct < 4; ++ct) {
        const __bf16* vp =
            vbase + (size_t)(ct * 16 + l15) * S_LEN + kbase + quad * 8;
        oc[ct] = MFMA16(pa, *(const bf16x8*)vp, oc[ct]);
      }
    }
  }

  int orow = b * S_LEN + q0 + wv * 16 + quad * 4;
  #pragma unroll
  for (int ct = 0; ct < 4; ++ct) {
    int col = hh * HDIM + ct * 16 + l15;
    #pragma unroll
    for (int r = 0; r < 4; ++r)
      ctx[(size_t)(orow + r) * HID + col] = (__bf16)oc[ct][r];
  }
}

// ---------------------------------------------------------------------------
// launch
// ---------------------------------------------------------------------------
extern "C" void kernel_launch(void* const* d_in, const int* in_sizes, int n_in,
                              void* d_out, int out_size, void* d_ws, size_t ws_size,
                              hipStream_t stream) {
  const int*   input_ids = (const int*)d_in[0];
  const int*   type_ids  = (const int*)d_in[1];
  const float* word_emb  = (const float*)d_in[2];
  const float* pos_emb   = (const float*)d_in[3];
  const float* type_emb  = (const float*)d_in[4];
  const float* eln_s     = (const float*)d_in[5];
  const float* eln_b     = (const float*)d_in[6];
  const float* wq = (const float*)d_in[7];
  const float* bq = (const float*)d_in[8];
  const float* wk = (const float*)d_in[9];
  const float* bk = (const float*)d_in[10];
  const float* wv = (const float*)d_in[11];
  const float* bv = (const float*)d_in[12];
  const float* wo = (const float*)d_in[13];
  const float* bo = (const float*)d_in[14];
  const float* l1s = (const float*)d_in[15];
  const float* l1b = (const float*)d_in[16];
  const float* w1  = (const float*)d_in[17];
  const float* b1  = (const float*)d_in[18];
  const float* w2  = (const float*)d_in[19];
  const float* b2  = (const float*)d_in[20];
  const float* l2s = (const float*)d_in[21];
  const float* l2b = (const float*)d_in[22];

  // ---- workspace carve-up ----
  char* p = (char*)d_ws;
  float*   h32    = (float*)p;            p += (size_t)NTOK * HID * 4;
  float*   tmp32  = (float*)p;            p += (size_t)NTOK * HID * 4 * 2; // p0,p1
  float*   tmp32b = tmp32 + (size_t)NTOK * HID;   // split-K partial 1
  __bf16*  vT16   = (__bf16*)tmp32;       // alias: vT live only during attn
  __bf16*  h16    = (__bf16*)p;           p += (size_t)NTOK * HID * 2;
  __bf16*  qkv16  = (__bf16*)p;           p += (size_t)NTOK * QKVN * 2;
  __bf16*  ctx16  = (__bf16*)p;           p += (size_t)NTOK * HID * 2;
  __bf16*  ffn16  = qkv16;                // alias qkv16+ctx16 contiguously
  float*   qkvb12 = (float*)p;            p += (size_t)NLAYER * QKVN * 4;
  float*   mb     = (float*)p;            p += (size_t)NTOK * 4;

  const size_t WHH = (size_t)HID * HID;
  const size_t WHF = (size_t)HID * FFN_DIM;
  const size_t WQKV = (size_t)QKVN * HID;

  // weight buffers: batched over all layers if ws is big enough
  size_t used = (size_t)(p - (char*)d_ws);
  size_t needB = used + (WQKV + WHH + 2 * WHF) * 2 * NLAYER + 256;
  int batched = (ws_size >= needB) ? 1 : 0;
  int nl = batched ? NLAYER : 1;
  __bf16* wTall  = (__bf16*)p;  p += WQKV * 2 * nl;
  __bf16* woTall = (__bf16*)p;  p += WHH * 2 * nl;
  __bf16* w1Tall = (__bf16*)p;  p += WHF * 2 * nl;
  __bf16* w2Tall = (__bf16*)p;  p += WHF * 2 * nl;
  size_t sQKV = batched ? WQKV : 0, sHH = batched ? WHH : 0,
         sHF = batched ? WHF : 0;

  dim3 blk(256);
  mask_kernel<<<dim3(NTOK / 256), blk, 0, stream>>>(input_ids, mb);
  pack_qkvb_kernel<<<dim3((NLAYER * QKVN + 255) / 256), blk, 0, stream>>>(
      bq, bk, bv, qkvb12);
  embed_ln_kernel<<<dim3(NTOK), blk, 0, stream>>>(
      input_ids, type_ids, word_emb, pos_emb, type_emb, eln_s, eln_b, h32, h16);

  if (batched) {
    tcvt4_kernel<<<dim3(HID / 32, HID / 32, 4 * NLAYER), blk, 0, stream>>>(
        wq, wk, wv, wo, wTall, woTall);
    tcvt_kernel<<<dim3(FFN_DIM / 32, HID / 32, NLAYER), blk, 0, stream>>>(
        w1, w1Tall, HID, FFN_DIM);
    tcvt_kernel<<<dim3(HID / 32, FFN_DIM / 32, NLAYER), blk, 0, stream>>>(
        w2, w2Tall, FFN_DIM, HID);
  }

  dim3 g_qkv(QKVN / 128, NTOK / 128, 1);      // 18 x 32
  dim3 g_ff1(FFN_DIM / 128, NTOK / 128, 1);   // 24 x 32
  dim3 g_wo(HID / 64, NTOK / 128, 1);         // 12 x 32
  dim3 g_ff2(HID / 64, NTOK / 128, 2);        // 12 x 32 x 2 (split-K)
  dim3 g_at(S_LEN / 64, NHEAD, 8);            // 8 x 12 x 8

  for (int l = 0; l < NLAYER; ++l) {
    size_t boff = (size_t)l * HID;
    if (!batched) {
      tcvt4_kernel<<<dim3(HID / 32, HID / 32, 4), blk, 0, stream>>>(
          wq + l * WHH, wk + l * WHH, wv + l * WHH, wo + l * WHH,
          wTall, woTall);
      tcvt_kernel<<<dim3(FFN_DIM / 32, HID / 32, 1), blk, 0, stream>>>(
          w1 + l * WHF, w1Tall, HID, FFN_DIM);
      tcvt_kernel<<<dim3(HID / 32, FFN_DIM / 32, 1), blk, 0, stream>>>(
          w2 + l * WHF, w2Tall, FFN_DIM, HID);
    }
    const __bf16* wTl  = wTall  + (size_t)l * sQKV;
    const __bf16* woTl = woTall + (size_t)l * sHH;
    const __bf16* w1Tl = w1Tall + (size_t)l * sHF;
    const __bf16* w2Tl = w2Tall + (size_t)l * sHF;

    // QKV with fused V-transpose into vT16
    mfma_gemm<3, 128><<<g_qkv, blk, 0, stream>>>(
        h16, wTl, qkvb12 + (size_t)l * QKVN, qkv16, vT16,
        NTOK, QKVN, HID, HID);
    attn_mfma<<<g_at, blk, 0, stream>>>(qkv16, vT16, mb, ctx16);
    mfma_gemm<0, 64><<<g_wo, blk, 0, stream>>>(
        ctx16, woTl, bo + boff, tmp32, nullptr, NTOK, HID, HID, HID);
    add_ln_kernel<<<dim3(NTOK), blk, 0, stream>>>(
        h32, tmp32, nullptr, l1s + boff, l1b + boff, h32, h16);
    mfma_gemm<2, 128><<<g_ff1, blk, 0, stream>>>(
        h16, w1Tl, b1 + (size_t)l * FFN_DIM, ffn16, nullptr,
        NTOK, FFN_DIM, HID, HID);
    // FFN2 split-K=2: partials in tmp32 / tmp32b, summed in add_ln
    mfma_gemm<0, 64><<<g_ff2, blk, 0, stream>>>(
        ffn16, w2Tl, b2 + boff, tmp32, nullptr, NTOK, HID, FFN_DIM,
        FFN_DIM / 2);
    float* dst = (l == NLAYER - 1) ? (float*)d_out : h32;
    add_ln_kernel<<<dim3(NTOK), blk, 0, stream>>>(
        h32, tmp32, tmp32b, l2s + boff, l2b + boff, dst, h16);
  }
}